// Round 3
// baseline (528.928 us; speedup 1.0000x reference)
//
#include <hip/hip_runtime.h>

typedef unsigned int uint32;
typedef unsigned short ushort16;

typedef __attribute__((ext_vector_type(8))) short short8;
typedef __attribute__((ext_vector_type(4))) float f32x4;

// ---------------------------------------------------------------------------
// GNN: h1 = relu((x + mean_agg(x)) @ W1 + b1)
//      h2 = relu((h1 + mean_agg(h1)) @ W2 + b2)
//      out = h2 @ Wp + bp
//
// R14: direct-CSR preprocessing (no buckets, no ebuf, no coop):
//   count:  deg[t]++ via global atomics (1.6M over 100K addrs, low contention)
//           + fused Wt1/Wt2 transpose-cvt prep
//   alloc:  per-wave shuffle scan of deg + one global-cursor atomic per wave
//           -> start[] / cursor[] (CSR ranges need NOT be in node order)
//   scatter: csr[atomicAdd(&cursor[t],1)] = s  — fused with GEMM1 (independent
//           work: atomic-latency-bound scatter overlaps BW-bound GEMM).
// Keeps R13 agg/GEMM commute: y=x@W1 (f32 in, in-reg bf16 cvt, no cvt pass);
// h1=relu(y+agg(y)+b1); z=h1@W2; out fused into agg2 (128x5 proj).
// R13 coop post-mortem: grid.sync at 18% occupancy cost ~80us — reverted.
// ---------------------------------------------------------------------------

__device__ __forceinline__ ushort16 f2bf(float f) {
    uint32 u = __float_as_uint(f);
    u += 0x7fffu + ((u >> 16) & 1u);       // round-to-nearest-even
    return (ushort16)(u >> 16);
}
__device__ __forceinline__ float bfhi(uint32 u) { return __uint_as_float(u & 0xffff0000u); }
__device__ __forceinline__ float bflo(uint32 u) { return __uint_as_float(u << 16); }
__device__ __forceinline__ uint32 pack2(float a, float b) {
    return (uint32)f2bf(a) | ((uint32)f2bf(b) << 16);
}

union U16 { uint4 u; short8 s; };
__device__ __forceinline__ short8 ld_frag(const ushort16* p) {
    U16 x; x.u = *(const uint4*)p; return x.s;
}

#define ACC8(v) \
    acc[0] += bflo(v.x); acc[1] += bfhi(v.x); \
    acc[2] += bflo(v.y); acc[3] += bfhi(v.y); \
    acc[4] += bflo(v.z); acc[5] += bfhi(v.z); \
    acc[6] += bflo(v.w); acc[7] += bfhi(v.w);

// ---------------------------------------------------------------------------
// K1: degree count (+ Wt prep on the 2 extra blocks).
// Grid = CB + 2; block q-range covers E/4 int4 elements exactly.
// ---------------------------------------------------------------------------
__global__ __launch_bounds__(256)
void count_prep_kernel(const int* __restrict__ tgt, int* __restrict__ deg,
                       const float* __restrict__ W1, const float* __restrict__ W2,
                       ushort16* __restrict__ Wt1, ushort16* __restrict__ Wt2,
                       int E, int CB) {
    int tid = threadIdx.x, blk = blockIdx.x;
    if (blk >= CB) {   // Wt prep blocks
        const float* W = (blk - CB) ? W2 : W1;
        ushort16* Wt = (blk - CB) ? Wt2 : Wt1;
        for (int i = tid; i < 16384; i += 256) {
            int k = i >> 7, c = i & 127;
            Wt[c * 128 + k] = f2bf(W[i]);
        }
        return;
    }
    int q = blk * 256 + tid;
    if (q < E / 4) {
        int4 t = ((const int4*)tgt)[q];
        atomicAdd(&deg[t.x], 1);
        atomicAdd(&deg[t.y], 1);
        atomicAdd(&deg[t.z], 1);
        atomicAdd(&deg[t.w], 1);
    }
    if (blk == 0 && tid == 0) {
        for (int e = (E / 4) * 4; e < E; ++e) atomicAdd(&deg[tgt[e]], 1);
    }
}

// ---------------------------------------------------------------------------
// K2: range allocation. Per-wave inclusive shuffle scan of deg, one global
// cursor atomicAdd per wave, write start[] and cursor[].
// ---------------------------------------------------------------------------
__global__ __launch_bounds__(256)
void alloc_kernel(const int* __restrict__ deg, int* __restrict__ start,
                  int* __restrict__ cursor, int* __restrict__ gcur, int N) {
    int i = blockIdx.x * 256 + threadIdx.x;
    int lane = threadIdx.x & 63;
    int d = (i < N) ? deg[i] : 0;
    int incl = d;
#pragma unroll
    for (int o = 1; o < 64; o <<= 1) {
        int t = __shfl_up(incl, o, 64);
        if (lane >= o) incl += t;
    }
    int total = __shfl(incl, 63, 64);
    int base = 0;
    if (lane == 63) base = atomicAdd(gcur, total);
    base = __shfl(base, 63, 64);
    int st = base + incl - d;
    if (i < N) { start[i] = st; cursor[i] = st; }
}

// ---------------------------------------------------------------------------
// GEMM device body: C[M,128] = A[M,128] @ W (raw) via mfma_f32_16x16x32_bf16.
// INF32: A f32 (in-register bf16 cvt); else A bf16. Wave = 16 rows.
// ---------------------------------------------------------------------------
template<int INF32>
__device__ __forceinline__
void gemm_body(const void* __restrict__ Asrc, const ushort16* __restrict__ Wt,
               int M, ushort16* __restrict__ outB, int bid) {
    const int tid = threadIdx.x;
    const int lane = tid & 63;
    const int wave = tid >> 6;
    const int l15 = lane & 15;
    const int quad = lane >> 4;
    const int r0 = bid * 64 + wave * 16;

    int arow = r0 + l15;
    if (arow >= M) arow = M - 1;

    short8 afr[4];
    if (INF32) {
        const float* ap = (const float*)Asrc + (size_t)arow * 128 + quad * 8;
#pragma unroll
        for (int kt = 0; kt < 4; ++kt) {
            float4 a0 = *(const float4*)(ap + kt * 32);
            float4 a1 = *(const float4*)(ap + kt * 32 + 4);
            short8 f;
            f[0] = (short)f2bf(a0.x); f[1] = (short)f2bf(a0.y);
            f[2] = (short)f2bf(a0.z); f[3] = (short)f2bf(a0.w);
            f[4] = (short)f2bf(a1.x); f[5] = (short)f2bf(a1.y);
            f[6] = (short)f2bf(a1.z); f[7] = (short)f2bf(a1.w);
            afr[kt] = f;
        }
    } else {
        const ushort16* aptr = (const ushort16*)Asrc + (size_t)arow * 128 + quad * 8;
#pragma unroll
        for (int kt = 0; kt < 4; ++kt) afr[kt] = ld_frag(aptr + kt * 32);
    }

    f32x4 acc[8];
#pragma unroll
    for (int t = 0; t < 8; ++t) acc[t] = (f32x4){0.f, 0.f, 0.f, 0.f};

#pragma unroll
    for (int t = 0; t < 8; ++t) {
        const ushort16* bptr = Wt + (size_t)(16 * t + l15) * 128 + quad * 8;
        short8 b0 = ld_frag(bptr);
        short8 b1 = ld_frag(bptr + 32);
        short8 b2 = ld_frag(bptr + 64);
        short8 b3 = ld_frag(bptr + 96);
        acc[t] = __builtin_amdgcn_mfma_f32_16x16x32_bf16(afr[0], b0, acc[t], 0, 0, 0);
        acc[t] = __builtin_amdgcn_mfma_f32_16x16x32_bf16(afr[1], b1, acc[t], 0, 0, 0);
        acc[t] = __builtin_amdgcn_mfma_f32_16x16x32_bf16(afr[2], b2, acc[t], 0, 0, 0);
        acc[t] = __builtin_amdgcn_mfma_f32_16x16x32_bf16(afr[3], b3, acc[t], 0, 0, 0);
    }

#pragma unroll
    for (int t = 0; t < 8; ++t) {
        float ov[4];
        ov[0] = acc[t].x; ov[1] = acc[t].y; ov[2] = acc[t].z; ov[3] = acc[t].w;
#pragma unroll
        for (int r = 0; r < 4; ++r) {
            float nb = __shfl_xor(ov[r], 1, 64);
            int row = r0 + quad * 4 + r;
            if (((l15 & 1) == 0) && row < M) {
                *(uint32*)(outB + (size_t)row * 128 + 16 * t + l15) = pack2(ov[r], nb);
            }
        }
    }
}

// ---------------------------------------------------------------------------
// K3: fat kernel — blocks < S scatter edges into CSR; blocks >= S do GEMM1.
// Independent work items; scatter is atomic-latency-bound, GEMM1 BW-bound.
// ---------------------------------------------------------------------------
__global__ __launch_bounds__(256)
void scatter_gemm1_kernel(const int* __restrict__ src, const int* __restrict__ tgt,
                          int* __restrict__ cursor, int* __restrict__ csr,
                          int E, int S,
                          const float* __restrict__ x, const ushort16* __restrict__ Wt1,
                          int M, ushort16* __restrict__ ybuf) {
    int blk = blockIdx.x;
    if (blk >= S) {
        gemm_body<1>(x, Wt1, M, ybuf, blk - S);
        return;
    }
    int tid = threadIdx.x;
    int q = blk * 256 + tid;
    if (q < E / 4) {
        int4 t = ((const int4*)tgt)[q];
        int4 s = ((const int4*)src)[q];
        int p0 = atomicAdd(&cursor[t.x], 1);
        int p1 = atomicAdd(&cursor[t.y], 1);
        int p2 = atomicAdd(&cursor[t.z], 1);
        int p3 = atomicAdd(&cursor[t.w], 1);
        csr[p0] = s.x;
        csr[p1] = s.y;
        csr[p2] = s.z;
        csr[p3] = s.w;
    }
    if (blk == 0 && tid == 0) {
        for (int e = (E / 4) * 4; e < E; ++e) {
            int p = atomicAdd(&cursor[tgt[e]], 1);
            csr[p] = src[e];
        }
    }
}

// standalone GEMM (layer 2)
template<int INF32>
__global__ __launch_bounds__(256)
void gemm_raw_kernel(const void* __restrict__ Asrc, const ushort16* __restrict__ Wt,
                     int M, ushort16* __restrict__ outB) {
    gemm_body<INF32>(Asrc, Wt, M, outB, blockIdx.x);
}

// ---------------------------------------------------------------------------
// agg + epilogue: h = relu(in_t + mean_{s in N(t)} in_s + bias)
// PROJ=0: write h bf16 row-major.  PROJ=1: out_t = h @ Wp + bp (f32 [N,5]).
// One wave per node; 8 edges in flight.
// ---------------------------------------------------------------------------
template<int PROJ>
__global__ __launch_bounds__(256, 4)
void agg_fuse_kernel(const ushort16* __restrict__ hb,
                     const int* __restrict__ start, const int* __restrict__ degv,
                     const int* __restrict__ csr,
                     const float* __restrict__ bias,
                     uint32* __restrict__ outb,
                     const float* __restrict__ Wp, const float* __restrict__ bp,
                     float* __restrict__ outP, int N) {
    int wid = (blockIdx.x * 256 + threadIdx.x) >> 6;
    int lane = threadIdx.x & 63;
    if (wid >= N) return;
    int g = lane >> 4, sl = lane & 15;
    int s0 = start[wid];
    int deg = degv[wid];
    int fi = sl * 4 + g;
    uint32 su = ((const uint32*)hb)[(size_t)wid * 64 + fi];

    float acc[8];
#pragma unroll
    for (int j = 0; j < 8; ++j) acc[j] = 0.f;

    int base = 0;
    for (; base + 8 <= deg; base += 8) {
        int i0 = csr[s0 + base + g];
        int i1 = csr[s0 + base + 4 + g];
        uint4 v0 = *(const uint4*)(hb + (size_t)i0 * 128 + sl * 8);
        uint4 v1 = *(const uint4*)(hb + (size_t)i1 * 128 + sl * 8);
        ACC8(v0); ACC8(v1);
    }
    for (; base < deg; base += 4) {
        int e = base + g;
        if (e < deg) {
            int s = csr[s0 + e];
            uint4 v = *(const uint4*)(hb + (size_t)s * 128 + sl * 8);
            ACC8(v);
        }
    }
#pragma unroll
    for (int j = 0; j < 8; ++j) {
        acc[j] += __shfl_xor(acc[j], 16, 64);
        acc[j] += __shfl_xor(acc[j], 32, 64);
    }
    float inv = 1.f / fmaxf((float)deg, 1.f);
    float ax = (g == 0) ? acc[0] : (g == 1) ? acc[2] : (g == 2) ? acc[4] : acc[6];
    float ay = (g == 0) ? acc[1] : (g == 1) ? acc[3] : (g == 2) ? acc[5] : acc[7];

    float ha = fmaxf(bflo(su) + ax * inv + bias[2 * fi],     0.f);
    float hc = fmaxf(bfhi(su) + ay * inv + bias[2 * fi + 1], 0.f);

    if (!PROJ) {
        outb[(size_t)wid * 64 + fi] = pack2(ha, hc);
    } else {
        float p[5];
#pragma unroll
        for (int j = 0; j < 5; ++j)
            p[j] = ha * Wp[(2 * fi) * 5 + j] + hc * Wp[(2 * fi + 1) * 5 + j];
#pragma unroll
        for (int m = 1; m <= 32; m <<= 1)
#pragma unroll
            for (int j = 0; j < 5; ++j) p[j] += __shfl_xor(p[j], m, 64);
        if (lane == 0) {
#pragma unroll
            for (int j = 0; j < 5; ++j) outP[(size_t)wid * 5 + j] = p[j] + bp[j];
        }
    }
}

extern "C" void kernel_launch(void* const* d_in, const int* in_sizes, int n_in,
                              void* d_out, int out_size, void* d_ws, size_t ws_size,
                              hipStream_t stream) {
    const float* x     = (const float*)d_in[0];
    const int*   edges = (const int*)d_in[1];
    const float* W1    = (const float*)d_in[2];
    const float* b1    = (const float*)d_in[3];
    const float* W2    = (const float*)d_in[4];
    const float* b2    = (const float*)d_in[5];
    const float* Wp    = (const float*)d_in[6];
    const float* bp    = (const float*)d_in[7];
    float* out = (float*)d_out;

    int N = in_sizes[0] / 128;   // 100000
    int E = in_sizes[1] / 2;     // 1600000
    const int* src = edges;
    const int* tgt = edges + E;

    char* ws = (char*)d_ws;
    size_t off = 0;
    auto alloc = [&](size_t bytes) {
        char* p = ws + off;
        off = (off + bytes + 255) & ~(size_t)255;
        return p;
    };
    int*      deg     = (int*)alloc((size_t)(N + 1) * 4);  // deg[N] = global cursor
    int*      start   = (int*)alloc((size_t)N * 4);
    int*      cursor  = (int*)alloc((size_t)N * 4);
    int*      csr     = (int*)alloc((size_t)E * 4);
    ushort16* ybuf    = (ushort16*)alloc((size_t)N * 128 * 2);  // y, later z
    ushort16* h1      = (ushort16*)alloc((size_t)N * 128 * 2);
    ushort16* Wt1     = (ushort16*)alloc(128 * 128 * 2);
    ushort16* Wt2     = (ushort16*)alloc(128 * 128 * 2);
    int*      gcur    = deg + N;
    (void)ws_size;

    const int CB = (E / 4 + 255) / 256;          // count blocks (1563)
    const int AB = (N + 255) / 256;              // alloc blocks (391)
    const int S  = CB;                           // scatter blocks
    const int gemmBlocks = (N + 63) / 64;        // 1563
    const int aggBlocks  = (N + 3) / 4;          // 25000

    hipMemsetAsync(deg, 0, (size_t)(N + 1) * 4, stream);
    // K1: degree count + Wt prep
    count_prep_kernel<<<CB + 2, 256, 0, stream>>>(tgt, deg, W1, W2, Wt1, Wt2, E, CB);
    // K2: CSR range allocation (wave scan + global cursor)
    alloc_kernel<<<AB, 256, 0, stream>>>(deg, start, cursor, gcur, N);
    // K3: scatter -> csr  ||  y = x @ W1 (f32 in, bf16 out)
    scatter_gemm1_kernel<<<S + gemmBlocks, 256, 0, stream>>>(src, tgt, cursor, csr,
                                                             E, S, x, Wt1, N, ybuf);
    // K4: h1 = relu(y + agg(y) + b1)
    agg_fuse_kernel<0><<<aggBlocks, 256, 0, stream>>>(ybuf, start, deg, csr, b1,
                                                      (uint32*)h1, nullptr, nullptr,
                                                      nullptr, N);
    // K5: z = h1 @ W2 (bf16 in, bf16 out, reuse ybuf)
    gemm_raw_kernel<0><<<gemmBlocks, 256, 0, stream>>>(h1, Wt2, N, ybuf);
    // K6: h2 = relu(z + agg(z) + b2); out = h2 @ Wp + bp
    agg_fuse_kernel<1><<<aggBlocks, 256, 0, stream>>>(ybuf, start, deg, csr, b2,
                                                      nullptr, Wp, bp, out, N);
}

// Round 5
// 387.260 us; speedup vs baseline: 1.3658x; 1.3658x over previous
//
#include <hip/hip_runtime.h>

typedef unsigned int uint32;
typedef unsigned short ushort16;

typedef __attribute__((ext_vector_type(8))) short short8;
typedef __attribute__((ext_vector_type(4))) float f32x4;

// ---------------------------------------------------------------------------
// GNN: h1 = relu((x + mean_agg(x)) @ W1 + b1)
//      h2 = relu((h1 + mean_agg(h1)) @ W2 + b2)
//      out = h2 @ Wp + bp
//
// R15: region-partitioned CSR build (write-locality fix for R14).
//  R14 post-mortem: direct csr[atomicAdd(cursor[t])] = s scattered 4B writes
//  across 6.4MB from all XCDs -> WRITE_SIZE 131MB (16x amplification, line
//  ping-pong across non-coherent per-XCD L2s); scatter_gemm1 = 190us.
//  Fix: two-level locality.
//   K1: per-block (8192-edge chunk) LDS count into R=49 regions (t>>11),
//       reserve per-block contiguous ranges (49 atomics/block), scatter
//       (s,t) into OWN ranges -> full-line write-backs, one writer per line.
//   K2: one block per region (2048 nodes, ~33K edges, ~130KB csr window =
//       single-XCD-L2 resident): LDS deg hist -> in-block 2048-scan ->
//       start[]/deg[] -> LDS-cursor scatter csr. GEMM1 fused as blocks >= R
//       (independent; overlaps). No global cursor kernel, no colscan.
//  Keeps R13 commute: y=x@W1 (f32 in, in-reg cvt); h1=relu(y+agg(y)+b1);
//  z=h1@W2; agg2 fuses bias/relu + 128x5 projection.
// R16: identical resubmit — R15 bench failed on container infra (no data).
// ---------------------------------------------------------------------------

#define RSH 11                 // 2048 nodes per region
#define NRG 2048               // nodes per region
#define CAP 49152              // rlist capacity per region (avg 32.7K, +90 sigma)
#define CH  8192               // edges per K1 partition block

__device__ __forceinline__ ushort16 f2bf(float f) {
    uint32 u = __float_as_uint(f);
    u += 0x7fffu + ((u >> 16) & 1u);       // round-to-nearest-even
    return (ushort16)(u >> 16);
}
__device__ __forceinline__ float bfhi(uint32 u) { return __uint_as_float(u & 0xffff0000u); }
__device__ __forceinline__ float bflo(uint32 u) { return __uint_as_float(u << 16); }
__device__ __forceinline__ uint32 pack2(float a, float b) {
    return (uint32)f2bf(a) | ((uint32)f2bf(b) << 16);
}

union U16 { uint4 u; short8 s; };
__device__ __forceinline__ short8 ld_frag(const ushort16* p) {
    U16 x; x.u = *(const uint4*)p; return x.s;
}

#define ACC8(v) \
    acc[0] += bflo(v.x); acc[1] += bfhi(v.x); \
    acc[2] += bflo(v.y); acc[3] += bfhi(v.y); \
    acc[4] += bflo(v.z); acc[5] += bfhi(v.z); \
    acc[6] += bflo(v.w); acc[7] += bfhi(v.w);

// ---------------------------------------------------------------------------
// K1: region partition (+ Wt prep on 2 extra blocks).
// ---------------------------------------------------------------------------
__global__ __launch_bounds__(256)
void partition_kernel(const int* __restrict__ src, const int* __restrict__ tgt,
                      uint2* __restrict__ rlist, int* __restrict__ rcursor,
                      const float* __restrict__ W1, const float* __restrict__ W2,
                      ushort16* __restrict__ Wt1, ushort16* __restrict__ Wt2,
                      int E, int PB, int R) {
    int tid = threadIdx.x, blk = blockIdx.x;
    if (blk >= PB) {   // Wt prep blocks
        const float* W = (blk - PB) ? W2 : W1;
        ushort16* Wt = (blk - PB) ? Wt2 : Wt1;
        for (int i = tid; i < 16384; i += 256) {
            int k = i >> 7, c = i & 127;
            Wt[c * 128 + k] = f2bf(W[i]);
        }
        return;
    }
    __shared__ int cnt[64];
    __shared__ int cbase[64];
    for (int r = tid; r < R; r += 256) cnt[r] = 0;
    __syncthreads();
    int e0 = blk * CH, e1 = min(e0 + CH, E);
    for (int e = e0 + tid; e < e1; e += 256)
        atomicAdd(&cnt[tgt[e] >> RSH], 1);
    __syncthreads();
    for (int r = tid; r < R; r += 256) {
        cbase[r] = atomicAdd(&rcursor[r], cnt[r]);
        cnt[r] = 0;   // reuse as local cursor
    }
    __syncthreads();
    for (int e = e0 + tid; e < e1; e += 256) {
        int t = tgt[e];
        int r = t >> RSH;
        int sl = cbase[r] + atomicAdd(&cnt[r], 1);
        if (sl < CAP) rlist[(size_t)r * CAP + sl] = make_uint2((uint32)src[e], (uint32)t);
    }
}

// ---------------------------------------------------------------------------
// GEMM device body: C[M,128] = A[M,128] @ W (raw) via mfma_f32_16x16x32_bf16.
// INF32: A f32 (in-register bf16 cvt); else A bf16. Wave = 16 rows.
// ---------------------------------------------------------------------------
template<int INF32>
__device__ __forceinline__
void gemm_body(const void* __restrict__ Asrc, const ushort16* __restrict__ Wt,
               int M, ushort16* __restrict__ outB, int bid) {
    const int tid = threadIdx.x;
    const int lane = tid & 63;
    const int wave = tid >> 6;
    const int l15 = lane & 15;
    const int quad = lane >> 4;
    const int r0 = bid * 64 + wave * 16;

    int arow = r0 + l15;
    if (arow >= M) arow = M - 1;

    short8 afr[4];
    if (INF32) {
        const float* ap = (const float*)Asrc + (size_t)arow * 128 + quad * 8;
#pragma unroll
        for (int kt = 0; kt < 4; ++kt) {
            float4 a0 = *(const float4*)(ap + kt * 32);
            float4 a1 = *(const float4*)(ap + kt * 32 + 4);
            short8 f;
            f[0] = (short)f2bf(a0.x); f[1] = (short)f2bf(a0.y);
            f[2] = (short)f2bf(a0.z); f[3] = (short)f2bf(a0.w);
            f[4] = (short)f2bf(a1.x); f[5] = (short)f2bf(a1.y);
            f[6] = (short)f2bf(a1.z); f[7] = (short)f2bf(a1.w);
            afr[kt] = f;
        }
    } else {
        const ushort16* aptr = (const ushort16*)Asrc + (size_t)arow * 128 + quad * 8;
#pragma unroll
        for (int kt = 0; kt < 4; ++kt) afr[kt] = ld_frag(aptr + kt * 32);
    }

    f32x4 acc[8];
#pragma unroll
    for (int t = 0; t < 8; ++t) acc[t] = (f32x4){0.f, 0.f, 0.f, 0.f};

#pragma unroll
    for (int t = 0; t < 8; ++t) {
        const ushort16* bptr = Wt + (size_t)(16 * t + l15) * 128 + quad * 8;
        short8 b0 = ld_frag(bptr);
        short8 b1 = ld_frag(bptr + 32);
        short8 b2 = ld_frag(bptr + 64);
        short8 b3 = ld_frag(bptr + 96);
        acc[t] = __builtin_amdgcn_mfma_f32_16x16x32_bf16(afr[0], b0, acc[t], 0, 0, 0);
        acc[t] = __builtin_amdgcn_mfma_f32_16x16x32_bf16(afr[1], b1, acc[t], 0, 0, 0);
        acc[t] = __builtin_amdgcn_mfma_f32_16x16x32_bf16(afr[2], b2, acc[t], 0, 0, 0);
        acc[t] = __builtin_amdgcn_mfma_f32_16x16x32_bf16(afr[3], b3, acc[t], 0, 0, 0);
    }

#pragma unroll
    for (int t = 0; t < 8; ++t) {
        float ov[4];
        ov[0] = acc[t].x; ov[1] = acc[t].y; ov[2] = acc[t].z; ov[3] = acc[t].w;
#pragma unroll
        for (int r = 0; r < 4; ++r) {
            float nb = __shfl_xor(ov[r], 1, 64);
            int row = r0 + quad * 4 + r;
            if (((l15 & 1) == 0) && row < M) {
                *(uint32*)(outB + (size_t)row * 128 + 16 * t + l15) = pack2(ov[r], nb);
            }
        }
    }
}

// ---------------------------------------------------------------------------
// K2: blocks < R: per-region CSR build (hist -> scan -> start/deg -> scatter).
//     blocks >= R: GEMM1 (y = x @ W1, f32 in, bf16 out).
// ---------------------------------------------------------------------------
__global__ __launch_bounds__(256)
void csr_gemm1_kernel(const uint2* __restrict__ rlist, const int* __restrict__ rcursor,
                      int* __restrict__ start, int* __restrict__ deg,
                      int* __restrict__ csr, int N, int R,
                      const float* __restrict__ x, const ushort16* __restrict__ Wt1,
                      ushort16* __restrict__ ybuf) {
    int blk = blockIdx.x;
    if (blk >= R) {
        gemm_body<1>(x, Wt1, N, ybuf, blk - R);
        return;
    }
    int tid = threadIdx.x;
    __shared__ int hist[NRG];
    __shared__ int sd[256];
    __shared__ int carrySh;
    __shared__ int rbaseSh, countSh;

    int r = blk;
    if (tid == 0) {
        int rb = 0;
        for (int i = 0; i < r; ++i) rb += rcursor[i];
        rbaseSh = rb;
        countSh = min(rcursor[r], CAP);
    }
    for (int i = tid; i < NRG; i += 256) hist[i] = 0;
    __syncthreads();
    int count = countSh;
    int rbase = rbaseSh;
    const uint2* rl = rlist + (size_t)r * CAP;
    int n0 = r << RSH;

    // pass 1: degree histogram
    for (int i = tid; i < count; i += 256)
        atomicAdd(&hist[rl[i].y & (NRG - 1)], 1);
    __syncthreads();

    // exclusive scan of 2048 in 8 chunks of 256; emit start/deg; hist -> cursor
    if (tid == 0) carrySh = rbase;
    __syncthreads();
    for (int c = 0; c < 8; ++c) {
        int idx = c * 256 + tid;
        int v = hist[idx];
        int c0 = carrySh;
        sd[tid] = v;
        __syncthreads();
        for (int o = 1; o < 256; o <<= 1) {
            int t = (tid >= o) ? sd[tid - o] : 0;
            __syncthreads();
            sd[tid] += t;
            __syncthreads();
        }
        int excl = sd[tid] - v + c0;
        int tot = sd[255];
        int node = n0 + idx;
        if (node < N) { start[node] = excl; deg[node] = v; }
        hist[idx] = excl;   // becomes scatter cursor
        __syncthreads();
        if (tid == 0) carrySh = c0 + tot;
        __syncthreads();
    }

    // pass 2: scatter into own csr window (~130KB, single-L2-resident)
    for (int i = tid; i < count; i += 256) {
        uint2 e = rl[i];
        int p = atomicAdd(&hist[e.y & (NRG - 1)], 1);
        csr[p] = (int)e.x;
    }
}

// standalone GEMM (layer 2)
template<int INF32>
__global__ __launch_bounds__(256)
void gemm_raw_kernel(const void* __restrict__ Asrc, const ushort16* __restrict__ Wt,
                     int M, ushort16* __restrict__ outB) {
    gemm_body<INF32>(Asrc, Wt, M, outB, blockIdx.x);
}

// ---------------------------------------------------------------------------
// agg + epilogue: h = relu(in_t + mean_{s in N(t)} in_s + bias)
// PROJ=0: write h bf16 row-major.  PROJ=1: out_t = h @ Wp + bp (f32 [N,5]).
// One wave per node; 8 edges in flight.
// ---------------------------------------------------------------------------
template<int PROJ>
__global__ __launch_bounds__(256, 4)
void agg_fuse_kernel(const ushort16* __restrict__ hb,
                     const int* __restrict__ start, const int* __restrict__ degv,
                     const int* __restrict__ csr,
                     const float* __restrict__ bias,
                     uint32* __restrict__ outb,
                     const float* __restrict__ Wp, const float* __restrict__ bp,
                     float* __restrict__ outP, int N) {
    int wid = (blockIdx.x * 256 + threadIdx.x) >> 6;
    int lane = threadIdx.x & 63;
    if (wid >= N) return;
    int g = lane >> 4, sl = lane & 15;
    int s0 = start[wid];
    int deg = degv[wid];
    int fi = sl * 4 + g;
    uint32 su = ((const uint32*)hb)[(size_t)wid * 64 + fi];

    float acc[8];
#pragma unroll
    for (int j = 0; j < 8; ++j) acc[j] = 0.f;

    int base = 0;
    for (; base + 8 <= deg; base += 8) {
        int i0 = csr[s0 + base + g];
        int i1 = csr[s0 + base + 4 + g];
        uint4 v0 = *(const uint4*)(hb + (size_t)i0 * 128 + sl * 8);
        uint4 v1 = *(const uint4*)(hb + (size_t)i1 * 128 + sl * 8);
        ACC8(v0); ACC8(v1);
    }
    for (; base < deg; base += 4) {
        int e = base + g;
        if (e < deg) {
            int s = csr[s0 + e];
            uint4 v = *(const uint4*)(hb + (size_t)s * 128 + sl * 8);
            ACC8(v);
        }
    }
#pragma unroll
    for (int j = 0; j < 8; ++j) {
        acc[j] += __shfl_xor(acc[j], 16, 64);
        acc[j] += __shfl_xor(acc[j], 32, 64);
    }
    float inv = 1.f / fmaxf((float)deg, 1.f);
    float ax = (g == 0) ? acc[0] : (g == 1) ? acc[2] : (g == 2) ? acc[4] : acc[6];
    float ay = (g == 0) ? acc[1] : (g == 1) ? acc[3] : (g == 2) ? acc[5] : acc[7];

    float ha = fmaxf(bflo(su) + ax * inv + bias[2 * fi],     0.f);
    float hc = fmaxf(bfhi(su) + ay * inv + bias[2 * fi + 1], 0.f);

    if (!PROJ) {
        outb[(size_t)wid * 64 + fi] = pack2(ha, hc);
    } else {
        float p[5];
#pragma unroll
        for (int j = 0; j < 5; ++j)
            p[j] = ha * Wp[(2 * fi) * 5 + j] + hc * Wp[(2 * fi + 1) * 5 + j];
#pragma unroll
        for (int m = 1; m <= 32; m <<= 1)
#pragma unroll
            for (int j = 0; j < 5; ++j) p[j] += __shfl_xor(p[j], m, 64);
        if (lane == 0) {
#pragma unroll
            for (int j = 0; j < 5; ++j) outP[(size_t)wid * 5 + j] = p[j] + bp[j];
        }
    }
}

extern "C" void kernel_launch(void* const* d_in, const int* in_sizes, int n_in,
                              void* d_out, int out_size, void* d_ws, size_t ws_size,
                              hipStream_t stream) {
    const float* x     = (const float*)d_in[0];
    const int*   edges = (const int*)d_in[1];
    const float* W1    = (const float*)d_in[2];
    const float* b1    = (const float*)d_in[3];
    const float* W2    = (const float*)d_in[4];
    const float* b2    = (const float*)d_in[5];
    const float* Wp    = (const float*)d_in[6];
    const float* bp    = (const float*)d_in[7];
    float* out = (float*)d_out;

    int N = in_sizes[0] / 128;   // 100000
    int E = in_sizes[1] / 2;     // 1600000
    const int* src = edges;
    const int* tgt = edges + E;

    const int R  = (N + NRG - 1) >> RSH;     // regions (49)
    const int PB = (E + CH - 1) / CH;        // partition blocks (196)

    char* ws = (char*)d_ws;
    size_t off = 0;
    auto alloc = [&](size_t bytes) {
        char* p = ws + off;
        off = (off + bytes + 255) & ~(size_t)255;
        return p;
    };
    int*      deg     = (int*)alloc((size_t)N * 4);
    int*      start   = (int*)alloc((size_t)N * 4);
    int*      csr     = (int*)alloc((size_t)E * 4);
    uint2*    rlist   = (uint2*)alloc((size_t)R * CAP * 8);
    int*      rcursor = (int*)alloc(64 * 4);
    ushort16* ybuf    = (ushort16*)alloc((size_t)N * 128 * 2);  // y, later z
    ushort16* h1      = (ushort16*)alloc((size_t)N * 128 * 2);
    ushort16* Wt1     = (ushort16*)alloc(128 * 128 * 2);
    ushort16* Wt2     = (ushort16*)alloc(128 * 128 * 2);
    (void)ws_size;

    const int gemmBlocks = (N + 63) / 64;        // 1563
    const int aggBlocks  = (N + 3) / 4;          // 25000

    hipMemsetAsync(rcursor, 0, 64 * 4, stream);
    // K1: region partition + Wt prep
    partition_kernel<<<PB + 2, 256, 0, stream>>>(src, tgt, rlist, rcursor,
                                                 W1, W2, Wt1, Wt2, E, PB, R);
    // K2: per-region CSR build  ||  y = x @ W1
    csr_gemm1_kernel<<<R + gemmBlocks, 256, 0, stream>>>(rlist, rcursor, start, deg,
                                                         csr, N, R, x, Wt1, ybuf);
    // K3: h1 = relu(y + agg(y) + b1)
    agg_fuse_kernel<0><<<aggBlocks, 256, 0, stream>>>(ybuf, start, deg, csr, b1,
                                                      (uint32*)h1, nullptr, nullptr,
                                                      nullptr, N);
    // K4: z = h1 @ W2 (bf16 in, bf16 out, reuse ybuf)
    gemm_raw_kernel<0><<<gemmBlocks, 256, 0, stream>>>(h1, Wt2, N, ybuf);
    // K5: h2 = relu(z + agg(z) + b2); out = h2 @ Wp + bp
    agg_fuse_kernel<1><<<aggBlocks, 256, 0, stream>>>(ybuf, start, deg, csr, b2,
                                                      nullptr, Wp, bp, out, N);
}

// Round 6
// 325.271 us; speedup vs baseline: 1.6261x; 1.1906x over previous
//
#include <hip/hip_runtime.h>

typedef unsigned int uint32;
typedef unsigned short ushort16;

typedef __attribute__((ext_vector_type(8))) short short8;
typedef __attribute__((ext_vector_type(4))) float f32x4;

// ---------------------------------------------------------------------------
// GNN: h1 = relu((x + mean_agg(x)) @ W1 + b1)
//      h2 = relu((h1 + mean_agg(h1)) @ W2 + b2)
//      out = h2 @ Wp + bp
//
// R17: prep rebuilt for memory-level parallelism.
//  R15 post-mortem: csr_gemm1 101us @ VALUBusy 4.8%, occ 15% — the 49 region
//  blocks were 256-thr (1 wave/SIMD) serial load->atomic chains (~128 deps x
//  ~700cy); K1 (~140us by subtraction) had the same chains + 9.6K cross-XCD
//  same-line rcursor atomics + a 64-iter scalar Wt-prep chain. Latency, not BW.
//  Fix:
//   K1a count:   782 blocks (CH=2048), LDS cnt[49], NO global atomics;
//                hist[blk][r]. + Wt prep on 16 blocks w/ float4 loads.
//   K1b scan:    49 blocks column-scan hist over 782 blocks -> per-block
//                region-relative bases (in-place) + total[r]. (~3us)
//   K1c scatter: 782 blocks, int4 reads, LDS cursor, write (s,t) into own
//                reserved rlist ranges (write-local, full lines).
//   K2 fat:      1024-thr blocks. blocks<49: region CSR (16 waves = 4/SIMD,
//                4x-unrolled passes -> 8-deep MLP); blocks>=49: GEMM1
//                (wave-parametrized body, 256 rows/block).
//  Keeps R13 commute: y=x@W1 (f32 in, in-reg cvt); h1=relu(y+agg(y)+b1);
//  z=h1@W2; agg2 fuses bias/relu + 128x5 projection. No memsets.
// ---------------------------------------------------------------------------

#define RSH 11                 // 2048 nodes per region
#define NRG 2048               // nodes per region
#define CAP 49152              // rlist capacity per region (avg 32.7K)
#define CH  2048               // edges per partition block

__device__ __forceinline__ ushort16 f2bf(float f) {
    uint32 u = __float_as_uint(f);
    u += 0x7fffu + ((u >> 16) & 1u);       // round-to-nearest-even
    return (ushort16)(u >> 16);
}
__device__ __forceinline__ float bfhi(uint32 u) { return __uint_as_float(u & 0xffff0000u); }
__device__ __forceinline__ float bflo(uint32 u) { return __uint_as_float(u << 16); }
__device__ __forceinline__ uint32 pack2(float a, float b) {
    return (uint32)f2bf(a) | ((uint32)f2bf(b) << 16);
}

union U16 { uint4 u; short8 s; };
__device__ __forceinline__ short8 ld_frag(const ushort16* p) {
    U16 x; x.u = *(const uint4*)p; return x.s;
}

#define ACC8(v) \
    acc[0] += bflo(v.x); acc[1] += bfhi(v.x); \
    acc[2] += bflo(v.y); acc[3] += bfhi(v.y); \
    acc[4] += bflo(v.z); acc[5] += bfhi(v.z); \
    acc[6] += bflo(v.w); acc[7] += bfhi(v.w);

// ---------------------------------------------------------------------------
// K1a: per-block region count (LDS only) + Wt prep on 16 extra blocks.
// ---------------------------------------------------------------------------
__global__ __launch_bounds__(256)
void count_prep_kernel(const int* __restrict__ tgt, int* __restrict__ hist,
                       const float* __restrict__ W1, const float* __restrict__ W2,
                       ushort16* __restrict__ Wt1, ushort16* __restrict__ Wt2,
                       int E, int PB, int R) {
    int tid = threadIdx.x, blk = blockIdx.x;
    if (blk >= PB) {   // Wt prep: 16 blocks, 2048 floats each, float4 loads
        int idx = blk - PB;
        const float* W = (idx >> 3) ? W2 : W1;
        ushort16* Wt = (idx >> 3) ? Wt2 : Wt1;
        int i0 = (idx & 7) * 2048 + tid * 8;
        float4 a = *(const float4*)(W + i0);
        float4 b = *(const float4*)(W + i0 + 4);
        int k = i0 >> 7, col = i0 & 127;
        Wt[(col + 0) * 128 + k] = f2bf(a.x);
        Wt[(col + 1) * 128 + k] = f2bf(a.y);
        Wt[(col + 2) * 128 + k] = f2bf(a.z);
        Wt[(col + 3) * 128 + k] = f2bf(a.w);
        Wt[(col + 4) * 128 + k] = f2bf(b.x);
        Wt[(col + 5) * 128 + k] = f2bf(b.y);
        Wt[(col + 6) * 128 + k] = f2bf(b.z);
        Wt[(col + 7) * 128 + k] = f2bf(b.w);
        return;
    }
    __shared__ int cnt[64];
    if (tid < 64) cnt[tid] = 0;
    __syncthreads();
    int q0 = blk * (CH / 4), q1 = min(q0 + CH / 4, E / 4);
    for (int q = q0 + tid; q < q1; q += 256) {
        int4 t = ((const int4*)tgt)[q];
        atomicAdd(&cnt[t.x >> RSH], 1);
        atomicAdd(&cnt[t.y >> RSH], 1);
        atomicAdd(&cnt[t.z >> RSH], 1);
        atomicAdd(&cnt[t.w >> RSH], 1);
    }
    __syncthreads();
    if (tid < R) hist[(size_t)blk * 64 + tid] = cnt[tid];
}

// ---------------------------------------------------------------------------
// K1b: per-region exclusive column scan of hist over PB blocks (in place,
// region-relative) + total[r].
// ---------------------------------------------------------------------------
__global__ __launch_bounds__(256)
void scan_kernel(int* __restrict__ hist, int* __restrict__ total, int PB) {
    __shared__ int sd[256];
    __shared__ int carrySh;
    int r = blockIdx.x, tid = threadIdx.x;
    if (tid == 0) carrySh = 0;
    __syncthreads();
    int chunks = (PB + 255) >> 8;
    for (int ch = 0; ch < chunks; ++ch) {
        int g = ch * 256 + tid;
        int v = (g < PB) ? hist[(size_t)g * 64 + r] : 0;
        int c0 = carrySh;
        sd[tid] = v;
        __syncthreads();
        for (int o = 1; o < 256; o <<= 1) {
            int t = (tid >= o) ? sd[tid - o] : 0;
            __syncthreads();
            sd[tid] += t;
            __syncthreads();
        }
        if (g < PB) hist[(size_t)g * 64 + r] = sd[tid] - v + c0;
        int tot = sd[255];
        __syncthreads();
        if (tid == 0) carrySh = c0 + tot;
        __syncthreads();
    }
    if (tid == 0) total[r] = carrySh;
}

// ---------------------------------------------------------------------------
// K1c: scatter (src,tgt) into reserved per-block ranges of per-region lists.
// ---------------------------------------------------------------------------
__global__ __launch_bounds__(256)
void scatter_kernel(const int* __restrict__ src, const int* __restrict__ tgt,
                    const int* __restrict__ hist, uint2* __restrict__ rlist,
                    int E, int R) {
    __shared__ int cb[64];
    __shared__ int cnt[64];
    int tid = threadIdx.x, blk = blockIdx.x;
    if (tid < 64) {
        cnt[tid] = 0;
        cb[tid] = (tid < R) ? hist[(size_t)blk * 64 + tid] : 0;
    }
    __syncthreads();
    int q0 = blk * (CH / 4), q1 = min(q0 + CH / 4, E / 4);
    for (int q = q0 + tid; q < q1; q += 256) {
        int4 t = ((const int4*)tgt)[q];
        int4 s = ((const int4*)src)[q];
        int r0 = t.x >> RSH, r1 = t.y >> RSH, r2 = t.z >> RSH, r3 = t.w >> RSH;
        int l0 = atomicAdd(&cnt[r0], 1);
        int l1 = atomicAdd(&cnt[r1], 1);
        int l2 = atomicAdd(&cnt[r2], 1);
        int l3 = atomicAdd(&cnt[r3], 1);
        int p0 = cb[r0] + l0, p1 = cb[r1] + l1, p2 = cb[r2] + l2, p3 = cb[r3] + l3;
        if (p0 < CAP) rlist[(size_t)r0 * CAP + p0] = make_uint2((uint32)s.x, (uint32)t.x);
        if (p1 < CAP) rlist[(size_t)r1 * CAP + p1] = make_uint2((uint32)s.y, (uint32)t.y);
        if (p2 < CAP) rlist[(size_t)r2 * CAP + p2] = make_uint2((uint32)s.z, (uint32)t.z);
        if (p3 < CAP) rlist[(size_t)r3 * CAP + p3] = make_uint2((uint32)s.w, (uint32)t.w);
    }
}

// ---------------------------------------------------------------------------
// GEMM per-wave body: 16 rows x 128 cols at row base r0w.
// INF32: A f32 (in-register bf16 cvt); else A bf16 row-major.
// ---------------------------------------------------------------------------
template<int INF32>
__device__ __forceinline__
void gemm_rows(const void* __restrict__ Asrc, const ushort16* __restrict__ Wt,
               int M, ushort16* __restrict__ outB, int r0w) {
    const int lane = threadIdx.x & 63;
    const int l15 = lane & 15;
    const int quad = lane >> 4;

    int arow = r0w + l15;
    if (arow >= M) arow = M - 1;

    short8 afr[4];
    if (INF32) {
        const float* ap = (const float*)Asrc + (size_t)arow * 128 + quad * 8;
#pragma unroll
        for (int kt = 0; kt < 4; ++kt) {
            float4 a0 = *(const float4*)(ap + kt * 32);
            float4 a1 = *(const float4*)(ap + kt * 32 + 4);
            short8 f;
            f[0] = (short)f2bf(a0.x); f[1] = (short)f2bf(a0.y);
            f[2] = (short)f2bf(a0.z); f[3] = (short)f2bf(a0.w);
            f[4] = (short)f2bf(a1.x); f[5] = (short)f2bf(a1.y);
            f[6] = (short)f2bf(a1.z); f[7] = (short)f2bf(a1.w);
            afr[kt] = f;
        }
    } else {
        const ushort16* aptr = (const ushort16*)Asrc + (size_t)arow * 128 + quad * 8;
#pragma unroll
        for (int kt = 0; kt < 4; ++kt) afr[kt] = ld_frag(aptr + kt * 32);
    }

    f32x4 acc[8];
#pragma unroll
    for (int t = 0; t < 8; ++t) acc[t] = (f32x4){0.f, 0.f, 0.f, 0.f};

#pragma unroll
    for (int t = 0; t < 8; ++t) {
        const ushort16* bptr = Wt + (size_t)(16 * t + l15) * 128 + quad * 8;
        short8 b0 = ld_frag(bptr);
        short8 b1 = ld_frag(bptr + 32);
        short8 b2 = ld_frag(bptr + 64);
        short8 b3 = ld_frag(bptr + 96);
        acc[t] = __builtin_amdgcn_mfma_f32_16x16x32_bf16(afr[0], b0, acc[t], 0, 0, 0);
        acc[t] = __builtin_amdgcn_mfma_f32_16x16x32_bf16(afr[1], b1, acc[t], 0, 0, 0);
        acc[t] = __builtin_amdgcn_mfma_f32_16x16x32_bf16(afr[2], b2, acc[t], 0, 0, 0);
        acc[t] = __builtin_amdgcn_mfma_f32_16x16x32_bf16(afr[3], b3, acc[t], 0, 0, 0);
    }

#pragma unroll
    for (int t = 0; t < 8; ++t) {
        float ov[4];
        ov[0] = acc[t].x; ov[1] = acc[t].y; ov[2] = acc[t].z; ov[3] = acc[t].w;
#pragma unroll
        for (int r = 0; r < 4; ++r) {
            float nb = __shfl_xor(ov[r], 1, 64);
            int row = r0w + quad * 4 + r;
            if (((l15 & 1) == 0) && row < M) {
                *(uint32*)(outB + (size_t)row * 128 + 16 * t + l15) = pack2(ov[r], nb);
            }
        }
    }
}

// ---------------------------------------------------------------------------
// K2 (1024 threads): blocks < R: region CSR (16 waves, 4x-unrolled passes);
//                    blocks >= R: GEMM1 (256 rows per block).
// ---------------------------------------------------------------------------
__global__ __launch_bounds__(1024)
void csr_gemm1_kernel(const uint2* __restrict__ rlist, const int* __restrict__ total,
                      int* __restrict__ start, int* __restrict__ deg,
                      int* __restrict__ csr, int N, int R,
                      const float* __restrict__ x, const ushort16* __restrict__ Wt1,
                      ushort16* __restrict__ ybuf) {
    int blk = blockIdx.x;
    int tid = threadIdx.x;
    if (blk >= R) {
        int gid = blk - R;
        gemm_rows<1>(x, Wt1, N, ybuf, gid * 256 + (tid >> 6) * 16);
        return;
    }
    __shared__ int hist[NRG];
    __shared__ int sd[1024];
    __shared__ int carrySh;
    __shared__ int rbaseSh, countSh;

    int r = blk;
    if (tid == 0) countSh = min(total[r], CAP);
    if (tid < 64) {   // wave 0: rbase = sum of totals of earlier regions
        int v = (tid < R) ? total[tid] : 0;
        int pm = (tid < r) ? v : 0;
#pragma unroll
        for (int o = 1; o < 64; o <<= 1) pm += __shfl_xor(pm, o, 64);
        if (tid == 0) rbaseSh = pm;
    }
    for (int i = tid; i < NRG; i += 1024) hist[i] = 0;
    __syncthreads();
    int count = countSh;
    const uint2* rl = rlist + (size_t)r * CAP;
    int n0 = r << RSH;

    // pass 1: degree histogram, 4x unrolled (8-deep MLP)
    {
        int i = tid;
        for (; i + 3072 < count; i += 4096) {
            uint2 a = rl[i], b = rl[i + 1024], c = rl[i + 2048], d = rl[i + 3072];
            atomicAdd(&hist[a.y & (NRG - 1)], 1);
            atomicAdd(&hist[b.y & (NRG - 1)], 1);
            atomicAdd(&hist[c.y & (NRG - 1)], 1);
            atomicAdd(&hist[d.y & (NRG - 1)], 1);
        }
        for (; i < count; i += 1024)
            atomicAdd(&hist[rl[i].y & (NRG - 1)], 1);
    }
    __syncthreads();

    // exclusive scan of 2048 in 2 chunks of 1024; emit start/deg; hist->cursor
    if (tid == 0) carrySh = rbaseSh;
    __syncthreads();
    for (int ch = 0; ch < 2; ++ch) {
        int idx = ch * 1024 + tid;
        int v = hist[idx];
        int c0 = carrySh;
        sd[tid] = v;
        __syncthreads();
        for (int o = 1; o < 1024; o <<= 1) {
            int t = (tid >= o) ? sd[tid - o] : 0;
            __syncthreads();
            sd[tid] += t;
            __syncthreads();
        }
        int excl = sd[tid] - v + c0;
        int tot = sd[1023];
        int node = n0 + idx;
        if (node < N) { start[node] = excl; deg[node] = v; }
        __syncthreads();
        hist[idx] = excl;   // becomes scatter cursor
        if (tid == 0) carrySh = c0 + tot;
        __syncthreads();
    }

    // pass 2: scatter into own csr window, 4x unrolled
    {
        int i = tid;
        for (; i + 3072 < count; i += 4096) {
            uint2 a = rl[i], b = rl[i + 1024], c = rl[i + 2048], d = rl[i + 3072];
            int pa = atomicAdd(&hist[a.y & (NRG - 1)], 1);
            int pb = atomicAdd(&hist[b.y & (NRG - 1)], 1);
            int pc = atomicAdd(&hist[c.y & (NRG - 1)], 1);
            int pd = atomicAdd(&hist[d.y & (NRG - 1)], 1);
            csr[pa] = (int)a.x;
            csr[pb] = (int)b.x;
            csr[pc] = (int)c.x;
            csr[pd] = (int)d.x;
        }
        for (; i < count; i += 1024) {
            uint2 e = rl[i];
            int p = atomicAdd(&hist[e.y & (NRG - 1)], 1);
            csr[p] = (int)e.x;
        }
    }
}

// standalone GEMM (layer 2), 256 threads
template<int INF32>
__global__ __launch_bounds__(256)
void gemm_raw_kernel(const void* __restrict__ Asrc, const ushort16* __restrict__ Wt,
                     int M, ushort16* __restrict__ outB) {
    gemm_rows<INF32>(Asrc, Wt, M, outB, blockIdx.x * 64 + (threadIdx.x >> 6) * 16);
}

// ---------------------------------------------------------------------------
// agg + epilogue: h = relu(in_t + mean_{s in N(t)} in_s + bias)
// PROJ=0: write h bf16 row-major.  PROJ=1: out_t = h @ Wp + bp (f32 [N,5]).
// One wave per node; 8 edges in flight.
// ---------------------------------------------------------------------------
template<int PROJ>
__global__ __launch_bounds__(256, 4)
void agg_fuse_kernel(const ushort16* __restrict__ hb,
                     const int* __restrict__ start, const int* __restrict__ degv,
                     const int* __restrict__ csr,
                     const float* __restrict__ bias,
                     uint32* __restrict__ outb,
                     const float* __restrict__ Wp, const float* __restrict__ bp,
                     float* __restrict__ outP, int N) {
    int wid = (blockIdx.x * 256 + threadIdx.x) >> 6;
    int lane = threadIdx.x & 63;
    if (wid >= N) return;
    int g = lane >> 4, sl = lane & 15;
    int s0 = start[wid];
    int deg = degv[wid];
    int fi = sl * 4 + g;
    uint32 su = ((const uint32*)hb)[(size_t)wid * 64 + fi];

    float acc[8];
#pragma unroll
    for (int j = 0; j < 8; ++j) acc[j] = 0.f;

    int base = 0;
    for (; base + 8 <= deg; base += 8) {
        int i0 = csr[s0 + base + g];
        int i1 = csr[s0 + base + 4 + g];
        uint4 v0 = *(const uint4*)(hb + (size_t)i0 * 128 + sl * 8);
        uint4 v1 = *(const uint4*)(hb + (size_t)i1 * 128 + sl * 8);
        ACC8(v0); ACC8(v1);
    }
    for (; base < deg; base += 4) {
        int e = base + g;
        if (e < deg) {
            int s = csr[s0 + e];
            uint4 v = *(const uint4*)(hb + (size_t)s * 128 + sl * 8);
            ACC8(v);
        }
    }
#pragma unroll
    for (int j = 0; j < 8; ++j) {
        acc[j] += __shfl_xor(acc[j], 16, 64);
        acc[j] += __shfl_xor(acc[j], 32, 64);
    }
    float inv = 1.f / fmaxf((float)deg, 1.f);
    float ax = (g == 0) ? acc[0] : (g == 1) ? acc[2] : (g == 2) ? acc[4] : acc[6];
    float ay = (g == 0) ? acc[1] : (g == 1) ? acc[3] : (g == 2) ? acc[5] : acc[7];

    float ha = fmaxf(bflo(su) + ax * inv + bias[2 * fi],     0.f);
    float hc = fmaxf(bfhi(su) + ay * inv + bias[2 * fi + 1], 0.f);

    if (!PROJ) {
        outb[(size_t)wid * 64 + fi] = pack2(ha, hc);
    } else {
        float p[5];
#pragma unroll
        for (int j = 0; j < 5; ++j)
            p[j] = ha * Wp[(2 * fi) * 5 + j] + hc * Wp[(2 * fi + 1) * 5 + j];
#pragma unroll
        for (int m = 1; m <= 32; m <<= 1)
#pragma unroll
            for (int j = 0; j < 5; ++j) p[j] += __shfl_xor(p[j], m, 64);
        if (lane == 0) {
#pragma unroll
            for (int j = 0; j < 5; ++j) outP[(size_t)wid * 5 + j] = p[j] + bp[j];
        }
    }
}

extern "C" void kernel_launch(void* const* d_in, const int* in_sizes, int n_in,
                              void* d_out, int out_size, void* d_ws, size_t ws_size,
                              hipStream_t stream) {
    const float* x     = (const float*)d_in[0];
    const int*   edges = (const int*)d_in[1];
    const float* W1    = (const float*)d_in[2];
    const float* b1    = (const float*)d_in[3];
    const float* W2    = (const float*)d_in[4];
    const float* b2    = (const float*)d_in[5];
    const float* Wp    = (const float*)d_in[6];
    const float* bp    = (const float*)d_in[7];
    float* out = (float*)d_out;

    int N = in_sizes[0] / 128;   // 100000
    int E = in_sizes[1] / 2;     // 1600000
    const int* src = edges;
    const int* tgt = edges + E;

    const int R  = (N + NRG - 1) >> RSH;     // regions (49)
    const int PB = (E + CH - 1) / CH;        // partition blocks (782)

    char* ws = (char*)d_ws;
    size_t off = 0;
    auto alloc = [&](size_t bytes) {
        char* p = ws + off;
        off = (off + bytes + 255) & ~(size_t)255;
        return p;
    };
    int*      deg     = (int*)alloc((size_t)N * 4);
    int*      start   = (int*)alloc((size_t)N * 4);
    int*      csr     = (int*)alloc((size_t)E * 4);
    uint2*    rlist   = (uint2*)alloc((size_t)R * CAP * 8);
    int*      hist    = (int*)alloc((size_t)PB * 64 * 4);
    int*      total   = (int*)alloc(64 * 4);
    ushort16* ybuf    = (ushort16*)alloc((size_t)N * 128 * 2);  // y, later z
    ushort16* h1      = (ushort16*)alloc((size_t)N * 128 * 2);
    ushort16* Wt1     = (ushort16*)alloc(128 * 128 * 2);
    ushort16* Wt2     = (ushort16*)alloc(128 * 128 * 2);
    (void)ws_size;

    const int g1Blocks   = (N + 255) / 256;      // 391 (256 rows per 1024-thr block)
    const int gemmBlocks = (N + 63) / 64;        // 1563
    const int aggBlocks  = (N + 3) / 4;          // 25000

    // K1a: region count (LDS only) + Wt prep (16 blocks)
    count_prep_kernel<<<PB + 16, 256, 0, stream>>>(tgt, hist, W1, W2, Wt1, Wt2,
                                                   E, PB, R);
    // K1b: per-region column scan -> per-block bases + total
    scan_kernel<<<R, 256, 0, stream>>>(hist, total, PB);
    // K1c: scatter into per-region lists (reserved ranges, no global atomics)
    scatter_kernel<<<PB, 256, 0, stream>>>(src, tgt, hist, rlist, E, R);
    // K2: per-region CSR build (1024 thr, unrolled)  ||  y = x @ W1
    csr_gemm1_kernel<<<R + g1Blocks, 1024, 0, stream>>>(rlist, total, start, deg,
                                                        csr, N, R, x, Wt1, ybuf);
    // K3: h1 = relu(y + agg(y) + b1)
    agg_fuse_kernel<0><<<aggBlocks, 256, 0, stream>>>(ybuf, start, deg, csr, b1,
                                                      (uint32*)h1, nullptr, nullptr,
                                                      nullptr, N);
    // K4: z = h1 @ W2 (bf16 in, bf16 out, reuse ybuf)
    gemm_raw_kernel<0><<<gemmBlocks, 256, 0, stream>>>(h1, Wt2, N, ybuf);
    // K5: h2 = relu(z + agg(z) + b2); out = h2 @ Wp + bp
    agg_fuse_kernel<1><<<aggBlocks, 256, 0, stream>>>(ybuf, start, deg, csr, b2,
                                                      nullptr, Wp, bp, out, N);
}